// Round 3
// baseline (418.899 us; speedup 1.0000x reference)
//
#include <hip/hip_runtime.h>
#include <hip/hip_bf16.h>
#include <hip/hip_fp16.h>

typedef _Float16 f16;
typedef _Float16 f16x8 __attribute__((ext_vector_type(8)));
typedef _Float16 f16x4 __attribute__((ext_vector_type(4)));
typedef float f32x4 __attribute__((ext_vector_type(4)));

#define N_OBJ 8192
#define HIDDEN 512
#define POOL 4096
#define N_REL 32768
#define N_RELCLS 51
#define NUM_OBJ_CLS 151

// ---------------- workspace layout (bytes, 256-aligned) ----------------
#define WS_E16    0UL
#define WS_WPE16  8388608UL
#define WS_WCATT  9437184UL
#define WS_FT     17825792UL
#define WS_P      26214400UL
#define WS_BIAS   160432128UL
#define WS_PREDS  160448512UL
#define WS_WFRAG  160481280UL

// ---------------- async global->LDS 16B ----------------
typedef const __attribute__((address_space(1))) void* gas_ptr;
typedef __attribute__((address_space(3))) void* las_ptr;
__device__ __forceinline__ void gl_lds16(const f16* g, f16* l) {
    __builtin_amdgcn_global_load_lds((gas_ptr)g, (las_ptr)l, 16, 0, 0);
}

// ---------------- fp32 -> fp16 convert (vectorized x4) ----------------
__global__ void k_convert(const float* __restrict__ in, f16* __restrict__ out, int n4) {
    int i = blockIdx.x * blockDim.x + threadIdx.x;
    if (i < n4) {
        f32x4 v = ((const f32x4*)in)[i];
        f16x4 h;
        h[0] = (f16)v[0]; h[1] = (f16)v[1]; h[2] = (f16)v[2]; h[3] = (f16)v[3];
        ((f16x4*)out)[i] = h;
    }
}

// ---------------- transpose + convert: in (R x C f32) -> out (C x R f16) ----------------
__global__ void k_transpose_cvt(const float* __restrict__ in, f16* __restrict__ out, int R, int C) {
    __shared__ float tile[32][33];
    int c0 = blockIdx.x * 32, r0 = blockIdx.y * 32;
    int tx = threadIdx.x, ty = threadIdx.y;   // block (32,8)
    #pragma unroll
    for (int i = 0; i < 4; i++)
        tile[ty + 8 * i][tx] = in[(size_t)(r0 + ty + 8 * i) * C + c0 + tx];
    __syncthreads();
    #pragma unroll
    for (int i = 0; i < 4; i++)
        out[(size_t)(c0 + ty + 8 * i) * R + r0 + tx] = (f16)tile[tx][ty + 8 * i];
}

// ---------------- combined bias: bias[c] = sum_j b_pe[j]*Wcat[j,c] + b_cat[c] ----------------
__global__ __launch_bounds__(256) void k_bias(const float* __restrict__ b_pe, const float* __restrict__ Wcat,
                                              const float* __restrict__ b_cat, float* __restrict__ bias) {
    __shared__ float red[8][32];
    int c = blockIdx.x * 32 + (threadIdx.x & 31);
    int jq = threadIdx.x >> 5;
    float acc = 0.0f;
    #pragma unroll 4
    for (int j = jq * 128; j < jq * 128 + 128; j++)
        acc += b_pe[j] * Wcat[(size_t)j * POOL + c];
    red[jq][threadIdx.x & 31] = acc;
    __syncthreads();
    if (jq == 0) {
        float s = b_cat[c];
        #pragma unroll
        for (int q = 0; q < 8; q++) s += red[q][threadIdx.x & 31];
        bias[c] = s;
    }
}

// ---------------- argmax of E @ W_obj + b_obj, f64 accumulation ----------------
// thread = (ks = tid>>5 in 0..7 : 64-wide K slice, jg = tid&31 : class group j = jj*31+jg, jg<31)
// f64-pipe-bound: 2560 FMA/thread, float4 LDS broadcasts, fixed-order deterministic reduce.
#define OPB 8
__global__ __launch_bounds__(256) void k_argmax(const float* __restrict__ E, const float* __restrict__ Wobj,
                                                const float* __restrict__ bobj, int* __restrict__ preds) {
    __shared__ float se[OPB * HIDDEN];           // 16 KB
    __shared__ double part[2][OPB][5][32];       // 20.5 KB
    __shared__ double redv[OPB][32];
    __shared__ int    redj[OPB][32];
    int tid = threadIdx.x;
    int o0 = blockIdx.x * OPB;
    const f32x4* Ev = (const f32x4*)(E + (size_t)o0 * HIDDEN);
    f32x4* sev = (f32x4*)se;
    #pragma unroll
    for (int i = 0; i < OPB * HIDDEN / 4 / 256; i++)
        sev[tid + i * 256] = Ev[tid + i * 256];
    __syncthreads();

    int ks = tid >> 5;
    int jg = tid & 31;
    int jgc = (jg < 31) ? jg : 30;
    double acc[OPB][5];
    #pragma unroll
    for (int o = 0; o < OPB; o++)
        #pragma unroll
        for (int jj = 0; jj < 5; jj++) acc[o][jj] = 0.0;

    int kbase = ks * 64;
    for (int k4 = 0; k4 < 16; k4++) {
        int k = kbase + k4 * 4;
        f32x4 ev[OPB];
        #pragma unroll
        for (int o = 0; o < OPB; o++) ev[o] = *(const f32x4*)(se + o * HIDDEN + k);
        #pragma unroll
        for (int kk = 0; kk < 4; kk++) {
            const float* wrow = Wobj + (size_t)(k + kk) * NUM_OBJ_CLS;
            float wv[5];
            #pragma unroll
            for (int jj = 0; jj < 5; jj++) {
                int j = jj * 31 + jgc;
                wv[jj] = wrow[(j < NUM_OBJ_CLS) ? j : (NUM_OBJ_CLS - 1)];
            }
            #pragma unroll
            for (int o = 0; o < OPB; o++) {
                double e = (double)ev[o][kk];
                #pragma unroll
                for (int jj = 0; jj < 5; jj++)
                    acc[o][jj] = fma(e, (double)wv[jj], acc[o][jj]);
            }
        }
    }

    // reduce 8 k-slices: shfl pairs, then 2-step LDS tree (fixed order, deterministic)
    #pragma unroll
    for (int o = 0; o < OPB; o++)
        #pragma unroll
        for (int jj = 0; jj < 5; jj++)
            acc[o][jj] += __shfl_xor(acc[o][jj], 32);
    int w = tid >> 6, lane = tid & 63;
    if (w >= 2 && lane < 32) {
        #pragma unroll
        for (int o = 0; o < OPB; o++)
            #pragma unroll
            for (int jj = 0; jj < 5; jj++) part[w - 2][o][jj][lane] = acc[o][jj];
    }
    __syncthreads();
    if (w < 2 && lane < 32) {
        #pragma unroll
        for (int o = 0; o < OPB; o++)
            #pragma unroll
            for (int jj = 0; jj < 5; jj++) acc[o][jj] += part[w][o][jj][lane];
    }
    __syncthreads();
    if (w == 1 && lane < 32) {
        #pragma unroll
        for (int o = 0; o < OPB; o++)
            #pragma unroll
            for (int jj = 0; jj < 5; jj++) part[0][o][jj][lane] = acc[o][jj];
    }
    __syncthreads();
    if (w == 0 && lane < 31) {
        #pragma unroll
        for (int o = 0; o < OPB; o++) {
            double best = -1e300; int bj = NUM_OBJ_CLS;
            #pragma unroll
            for (int jj = 0; jj < 5; jj++) {
                int j = jj * 31 + lane;
                if (j < NUM_OBJ_CLS) {
                    double v = acc[o][jj] + part[0][o][jj][lane] + (double)bobj[j];
                    if (v > best || (v == best && j < bj)) { best = v; bj = j; }
                }
            }
            redv[o][lane] = best; redj[o][lane] = bj;
        }
    }
    __syncthreads();
    if (tid < OPB) {
        int o = tid;
        double best = -1e300; int bj = NUM_OBJ_CLS;
        for (int g = 0; g < 31; g++) {
            double v = redv[o][g]; int j = redj[o][g];
            if (v > best || (v == best && j < bj)) { best = v; bj = j; }
        }
        preds[o0 + o] = bj;
    }
}

// ---------------- pack W_rel into MFMA B-fragment layout ----------------
__global__ void k_wrel_frag(const float* __restrict__ Wrel, f16* __restrict__ frag) {
    int lane = threadIdx.x & 63;
    int nt = threadIdx.x >> 6;
    int kstep = blockIdx.x;
    int n = nt * 16 + (lane & 15);
    int k0 = kstep * 32 + (lane >> 4) * 8;
    f16x8 v;
    #pragma unroll
    for (int jj = 0; jj < 8; jj++) {
        float w = (n < N_RELCLS) ? Wrel[(size_t)(k0 + jj) * N_RELCLS + n] : 0.0f;
        v[jj] = (f16)w;
    }
    ((f16x8*)frag)[(size_t)(kstep * 4 + nt) * 64 + lane] = v;
}

// ---------------- LDS-staged fp16 NT GEMM, m97 structure ----------------
template<bool SPLITM>
__global__ __launch_bounds__(256) void k_gemm(const f16* __restrict__ A, const f16* __restrict__ B,
                                              f16* __restrict__ C, const float* __restrict__ bias,
                                              int K, int lda, int ldb, int ldc,
                                              long aZ, long bZ, long cZ, int biasLimit) {
    __shared__ f16 As[128 * 64];
    __shared__ f16 Bs[128 * 64];
    long z = blockIdx.z;
    A += z * aZ; B += z * bZ; C += z * cZ;

    int tid = threadIdx.x;
    int w = tid >> 6, lane = tid & 63;
    int wm = w >> 1, wn = w & 1;
    int lr = lane & 15, lg = lane >> 4;
    int mBase = blockIdx.y * 128;
    int nBase = blockIdx.x * 128;

    const f16* aSrc[4]; const f16* bSrc[4];
    f16* aDst[4]; f16* bDst[4];
    #pragma unroll
    for (int p = 0; p < 4; p++) {
        int c = p * 256 + tid;
        int row = c >> 3, slot = c & 7;
        int scol = (slot ^ (row & 7)) * 8;   // inverse-swizzled global source
        aSrc[p] = A + (size_t)(mBase + row) * lda + scol;
        bSrc[p] = B + (size_t)(nBase + row) * ldb + scol;
        aDst[p] = As + p * 2048 + w * 512;   // wave-uniform, linear LDS dest
        bDst[p] = Bs + p * 2048 + w * 512;
    }

    int swz = (lr & 7) << 4;                 // per-lane read swizzle (bytes)
    f32x4 acc[4][4] = {};

    for (int k0 = 0; k0 < K; k0 += 64) {
        if (k0) __syncthreads();
        #pragma unroll
        for (int p = 0; p < 4; p++) {
            gl_lds16(aSrc[p] + k0, aDst[p]);
            gl_lds16(bSrc[p] + k0, bDst[p]);
        }
        __syncthreads();
        #pragma unroll
        for (int kh = 0; kh < 2; kh++) {
            f16x8 av[4], bv[4];
            int koff = ((kh * 64 + lg * 16) ^ swz) >> 1;
            #pragma unroll
            for (int i = 0; i < 4; i++) {
                av[i] = *(const f16x8*)(As + (wm * 64 + i * 16 + lr) * 64 + koff);
                bv[i] = *(const f16x8*)(Bs + (wn * 64 + i * 16 + lr) * 64 + koff);
            }
            #pragma unroll
            for (int i = 0; i < 4; i++)
                #pragma unroll
                for (int jj = 0; jj < 4; jj++)
                    acc[i][jj] = __builtin_amdgcn_mfma_f32_16x16x32_f16(av[i], bv[jj], acc[i][jj], 0, 0, 0);
        }
    }

    #pragma unroll
    for (int i = 0; i < 4; i++) {
        int mb = mBase + wm * 64 + i * 16 + lg * 4;
        f32x4 bi = {};
        if (bias && mb < biasLimit) bi = *(const f32x4*)(bias + mb);
        #pragma unroll
        for (int jj = 0; jj < 4; jj++) {
            int n = nBase + wn * 64 + jj * 16 + lr;
            f16x4 hv;
            #pragma unroll
            for (int r = 0; r < 4; r++) hv[r] = (f16)(acc[i][jj][r] + bi[r]);
            if (SPLITM) {
                size_t off = ((size_t)((mb >= POOL) ? N_OBJ : 0) + n) * POOL + (mb & (POOL - 1));
                *(f16x4*)(C + off) = hv;
            } else {
                *(f16x4*)(C + (size_t)n * ldc + mb) = hv;
            }
        }
    }
}

// ---------------- final fused kernel (K-split x2 for occupancy) ----------------
// out[r, 0:51] = ((P_h[h[r]] + P_t[t[r]]) * U[r]) @ Wrel + b_rel + freq_bias[lbl(r)]
// block: 4 waves = 2 row-groups x 2 K-halves; f32 partial combine in LDS.
__global__ __launch_bounds__(256, 4) void k_final(const f16* __restrict__ P, const float* __restrict__ U,
                                                  const int* __restrict__ relp, const int* __restrict__ preds,
                                                  const f16* __restrict__ wfrag, const float* __restrict__ brel,
                                                  const float* __restrict__ fbias, float* __restrict__ out) {
    __shared__ f32x4 sacc[2][64][4];   // 8 KB
    int w = threadIdx.x >> 6;
    int lane = threadIdx.x & 63;
    int rg = w & 1, kh = w >> 1;
    int lr = lane & 15, lg = lane >> 4;
    int r0 = blockIdx.x * 32 + rg * 16;
    int arow = r0 + lr;                       // row this lane supplies A-fragments for
    int h = relp[2 * arow], t = relp[2 * arow + 1];
    const f16* ph = P + (size_t)h * POOL;
    const f16* pt = P + (size_t)(N_OBJ + t) * POOL;
    const float* u = U + (size_t)arow * POOL;
    f32x4 acc[4] = {};
    int ksEnd = kh * 64 + 64;
    #pragma unroll 2
    for (int ks = kh * 64; ks < ksEnd; ks++) {
        int ka = ks * 32 + lg * 8;
        f16x8 vh = *(const f16x8*)(ph + ka);
        f16x8 vt = *(const f16x8*)(pt + ka);
        f32x4 u0 = __builtin_nontemporal_load((const f32x4*)(u + ka));
        f32x4 u1 = __builtin_nontemporal_load((const f32x4*)(u + ka + 4));
        f16x8 a;
        #pragma unroll
        for (int jj = 0; jj < 8; jj++) {
            float uu = (jj < 4) ? u0[jj] : u1[jj - 4];
            a[jj] = (f16)(((float)vh[jj] + (float)vt[jj]) * uu);
        }
        const f16x8* bf = (const f16x8*)wfrag + (size_t)ks * 4 * 64 + lane;
        #pragma unroll
        for (int nt = 0; nt < 4; nt++)
            acc[nt] = __builtin_amdgcn_mfma_f32_16x16x32_f16(a, bf[nt * 64], acc[nt], 0, 0, 0);
    }
    if (kh == 1) {
        #pragma unroll
        for (int nt = 0; nt < 4; nt++) sacc[rg][lane][nt] = acc[nt];
    }
    __syncthreads();
    if (kh == 0) {
        #pragma unroll
        for (int nt = 0; nt < 4; nt++) acc[nt] += sacc[rg][lane][nt];
        #pragma unroll
        for (int r = 0; r < 4; r++) {
            int row = r0 + lg * 4 + r;        // C-layout row for this lane/reg
            int h2 = relp[2 * row], t2 = relp[2 * row + 1];
            int lbl = preds[h2] * NUM_OBJ_CLS + preds[t2];
            const float* fb = fbias + (size_t)lbl * N_RELCLS;
            #pragma unroll
            for (int nt = 0; nt < 4; nt++) {
                int j = nt * 16 + lr;         // C-layout col
                if (j < N_RELCLS)
                    out[(size_t)row * N_RELCLS + j] = acc[nt][r] + brel[j] + fb[j];
            }
        }
    }
}

extern "C" void kernel_launch(void* const* d_in, const int* in_sizes, int n_in,
                              void* d_out, int out_size, void* d_ws, size_t ws_size,
                              hipStream_t stream) {
    const float* edge_ctx = (const float*)d_in[0];
    const int*   relp     = (const int*)d_in[1];
    const float* U        = (const float*)d_in[2];
    const float* Wobj     = (const float*)d_in[3];
    const float* bobj     = (const float*)d_in[4];
    const float* Wpe      = (const float*)d_in[5];
    const float* bpe      = (const float*)d_in[6];
    const float* Wcat     = (const float*)d_in[7];
    const float* bcat     = (const float*)d_in[8];
    const float* Wrel     = (const float*)d_in[9];
    const float* brel     = (const float*)d_in[10];
    const float* fbias    = (const float*)d_in[11];
    float* out = (float*)d_out;

    char* ws = (char*)d_ws;
    f16*   E16    = (f16*)(ws + WS_E16);
    f16*   Wpe16  = (f16*)(ws + WS_WPE16);
    f16*   WcatT  = (f16*)(ws + WS_WCATT);
    f16*   FT     = (f16*)(ws + WS_FT);
    f16*   P      = (f16*)(ws + WS_P);
    float* bias   = (float*)(ws + WS_BIAS);
    int*   preds  = (int*)(ws + WS_PREDS);
    f16*   wfrag  = (f16*)(ws + WS_WFRAG);

    // 1. converts
    k_convert<<<4096, 256, 0, stream>>>(edge_ctx, E16, N_OBJ * HIDDEN / 4);
    k_convert<<<512, 256, 0, stream>>>(Wpe, Wpe16, HIDDEN * 2 * HIDDEN / 4);
    // 2. Wcat transpose+convert
    k_transpose_cvt<<<dim3(POOL / 32, (2 * HIDDEN) / 32), dim3(32, 8), 0, stream>>>(Wcat, WcatT, 2 * HIDDEN, POOL);
    // 3. combined bias
    k_bias<<<POOL / 32, 256, 0, stream>>>(bpe, Wcat, bcat, bias);
    // 4. object class argmax (f64 accum)
    k_argmax<<<N_OBJ / OPB, 256, 0, stream>>>(edge_ctx, Wobj, bobj, preds);
    // 5. W_rel fragment packing
    k_wrel_frag<<<POOL / 32, 256, 0, stream>>>(Wrel, wfrag);
    // 6. fold (both parts, grid.z=2)
    k_gemm<false><<<dim3(POOL / 128, HIDDEN / 128, 2), 256, 0, stream>>>(
        Wpe16, WcatT, FT, nullptr, HIDDEN, 2 * HIDDEN, 2 * HIDDEN, HIDDEN,
        512L, 512L, (long)POOL * HIDDEN, 0);
    // 7. fused proj (M=8192 covers both parts)
    k_gemm<true><<<dim3(N_OBJ / 128, (2 * POOL) / 128, 1), 256, 0, stream>>>(
        FT, E16, P, bias, HIDDEN, HIDDEN, HIDDEN, POOL,
        0L, 0L, 0L, POOL);
    // 8. final fused gather + union-mult + GEMM4 + freq_bias
    k_final<<<N_REL / 32, 256, 0, stream>>>(P, U, relp, preds, wfrag, brel, fbias, out);
}

// Round 4
// 387.049 us; speedup vs baseline: 1.0823x; 1.0823x over previous
//
#include <hip/hip_runtime.h>
#include <hip/hip_bf16.h>
#include <hip/hip_fp16.h>

typedef _Float16 f16;
typedef _Float16 f16x8 __attribute__((ext_vector_type(8)));
typedef _Float16 f16x4 __attribute__((ext_vector_type(4)));
typedef float f32x4 __attribute__((ext_vector_type(4)));

#define N_OBJ 8192
#define HIDDEN 512
#define POOL 4096
#define N_REL 32768
#define N_RELCLS 51
#define NUM_OBJ_CLS 151

// ---------------- workspace layout (bytes, 256-aligned) ----------------
#define WS_E16    0UL
#define WS_WPE16  8388608UL
#define WS_WCATT  9437184UL
#define WS_FT     17825792UL
#define WS_P      26214400UL
#define WS_BIAS   160432128UL
#define WS_PREDS  160448512UL
#define WS_WFRAG  160481280UL

// ---------------- async global->LDS 16B ----------------
typedef const __attribute__((address_space(1))) void* gas_ptr;
typedef __attribute__((address_space(3))) void* las_ptr;
__device__ __forceinline__ void gl_lds16(const f16* g, f16* l) {
    __builtin_amdgcn_global_load_lds((gas_ptr)g, (las_ptr)l, 16, 0, 0);
}

// ---------------- fused prep: convE | convWpe | transposeWcat | bias | wrelfrag ----------------
// sections by blockIdx.x: [0,1024) convE, [1024,1152) convWpe, [1152,5248) transpose,
// [5248,5376) bias, [5376,5504) wrel_frag. All independent.
__global__ __launch_bounds__(256) void k_prep(const float* __restrict__ edge_ctx, const float* __restrict__ Wpe,
                                              const float* __restrict__ Wcat, const float* __restrict__ bpe,
                                              const float* __restrict__ bcat, const float* __restrict__ Wrel,
                                              f16* __restrict__ E16, f16* __restrict__ Wpe16,
                                              f16* __restrict__ WcatT, float* __restrict__ bias,
                                              f16* __restrict__ wfrag) {
    __shared__ float tile[32][33];
    __shared__ float red[8][32];
    int bid = blockIdx.x, tid = threadIdx.x;
    if (bid < 1024) {
        // convert edge_ctx -> E16 (4 f32x4 per thread)
        const f32x4* in = (const f32x4*)edge_ctx;
        f16x4* out = (f16x4*)E16;
        int base = bid * 1024 + tid;
        #pragma unroll
        for (int s = 0; s < 4; s++) {
            f32x4 v = in[base + s * 256];
            f16x4 h; h[0]=(f16)v[0]; h[1]=(f16)v[1]; h[2]=(f16)v[2]; h[3]=(f16)v[3];
            out[base + s * 256] = h;
        }
    } else if (bid < 1152) {
        // convert Wpe -> Wpe16
        const f32x4* in = (const f32x4*)Wpe;
        f16x4* out = (f16x4*)Wpe16;
        int base = (bid - 1024) * 1024 + tid;
        #pragma unroll
        for (int s = 0; s < 4; s++) {
            f32x4 v = in[base + s * 256];
            f16x4 h; h[0]=(f16)v[0]; h[1]=(f16)v[1]; h[2]=(f16)v[2]; h[3]=(f16)v[3];
            out[base + s * 256] = h;
        }
    } else if (bid < 5248) {
        // transpose+convert Wcat (1024 x 4096 f32) -> WcatT (4096 x 1024 f16)
        int t = bid - 1152;
        int c0 = (t & 127) * 32, r0 = (t >> 7) * 32;
        int tx = tid & 31, ty = tid >> 5;
        #pragma unroll
        for (int i = 0; i < 4; i++)
            tile[ty + 8 * i][tx] = Wcat[(size_t)(r0 + ty + 8 * i) * POOL + c0 + tx];
        __syncthreads();
        #pragma unroll
        for (int i = 0; i < 4; i++)
            WcatT[(size_t)(c0 + ty + 8 * i) * (2 * HIDDEN) + r0 + tx] = (f16)tile[tx][ty + 8 * i];
    } else if (bid < 5376) {
        // bias[c] = sum_j bpe[j]*Wcat[j,c] + bcat[c]
        int c = (bid - 5248) * 32 + (tid & 31);
        int jq = tid >> 5;
        float acc = 0.0f;
        #pragma unroll 4
        for (int j = jq * 128; j < jq * 128 + 128; j++)
            acc += bpe[j] * Wcat[(size_t)j * POOL + c];
        red[jq][tid & 31] = acc;
        __syncthreads();
        if (jq == 0) {
            float s = bcat[c];
            #pragma unroll
            for (int q = 0; q < 8; q++) s += red[q][tid & 31];
            bias[c] = s;
        }
    } else {
        // W_rel -> MFMA B-fragment layout
        int kstep = bid - 5376;
        int lane = tid & 63;
        int nt = tid >> 6;
        int n = nt * 16 + (lane & 15);
        int k0 = kstep * 32 + (lane >> 4) * 8;
        f16x8 v;
        #pragma unroll
        for (int jj = 0; jj < 8; jj++) {
            float w = (n < N_RELCLS) ? Wrel[(size_t)(k0 + jj) * N_RELCLS + n] : 0.0f;
            v[jj] = (f16)w;
        }
        ((f16x8*)wfrag)[(size_t)(kstep * 4 + nt) * 64 + lane] = v;
    }
}

// ---------------- argmax of E @ W_obj + b_obj, f64 accumulation ----------------
#define OPB 8
__global__ __launch_bounds__(256) void k_argmax(const float* __restrict__ E, const float* __restrict__ Wobj,
                                                const float* __restrict__ bobj, int* __restrict__ preds) {
    __shared__ float se[OPB * HIDDEN];           // 16 KB
    __shared__ double part[2][OPB][5][32];       // 20.5 KB
    __shared__ double redv[OPB][32];
    __shared__ int    redj[OPB][32];
    int tid = threadIdx.x;
    int o0 = blockIdx.x * OPB;
    const f32x4* Ev = (const f32x4*)(E + (size_t)o0 * HIDDEN);
    f32x4* sev = (f32x4*)se;
    #pragma unroll
    for (int i = 0; i < OPB * HIDDEN / 4 / 256; i++)
        sev[tid + i * 256] = Ev[tid + i * 256];
    __syncthreads();

    int ks = tid >> 5;
    int jg = tid & 31;
    int jgc = (jg < 31) ? jg : 30;
    double acc[OPB][5];
    #pragma unroll
    for (int o = 0; o < OPB; o++)
        #pragma unroll
        for (int jj = 0; jj < 5; jj++) acc[o][jj] = 0.0;

    int kbase = ks * 64;
    for (int k4 = 0; k4 < 16; k4++) {
        int k = kbase + k4 * 4;
        f32x4 ev[OPB];
        #pragma unroll
        for (int o = 0; o < OPB; o++) ev[o] = *(const f32x4*)(se + o * HIDDEN + k);
        #pragma unroll
        for (int kk = 0; kk < 4; kk++) {
            const float* wrow = Wobj + (size_t)(k + kk) * NUM_OBJ_CLS;
            float wv[5];
            #pragma unroll
            for (int jj = 0; jj < 5; jj++) {
                int j = jj * 31 + jgc;
                wv[jj] = wrow[(j < NUM_OBJ_CLS) ? j : (NUM_OBJ_CLS - 1)];
            }
            #pragma unroll
            for (int o = 0; o < OPB; o++) {
                double e = (double)ev[o][kk];
                #pragma unroll
                for (int jj = 0; jj < 5; jj++)
                    acc[o][jj] = fma(e, (double)wv[jj], acc[o][jj]);
            }
        }
    }

    #pragma unroll
    for (int o = 0; o < OPB; o++)
        #pragma unroll
        for (int jj = 0; jj < 5; jj++)
            acc[o][jj] += __shfl_xor(acc[o][jj], 32);
    int w = tid >> 6, lane = tid & 63;
    if (w >= 2 && lane < 32) {
        #pragma unroll
        for (int o = 0; o < OPB; o++)
            #pragma unroll
            for (int jj = 0; jj < 5; jj++) part[w - 2][o][jj][lane] = acc[o][jj];
    }
    __syncthreads();
    if (w < 2 && lane < 32) {
        #pragma unroll
        for (int o = 0; o < OPB; o++)
            #pragma unroll
            for (int jj = 0; jj < 5; jj++) acc[o][jj] += part[w][o][jj][lane];
    }
    __syncthreads();
    if (w == 1 && lane < 32) {
        #pragma unroll
        for (int o = 0; o < OPB; o++)
            #pragma unroll
            for (int jj = 0; jj < 5; jj++) part[0][o][jj][lane] = acc[o][jj];
    }
    __syncthreads();
    if (w == 0 && lane < 31) {
        #pragma unroll
        for (int o = 0; o < OPB; o++) {
            double best = -1e300; int bj = NUM_OBJ_CLS;
            #pragma unroll
            for (int jj = 0; jj < 5; jj++) {
                int j = jj * 31 + lane;
                if (j < NUM_OBJ_CLS) {
                    double v = acc[o][jj] + part[0][o][jj][lane] + (double)bobj[j];
                    if (v > best || (v == best && j < bj)) { best = v; bj = j; }
                }
            }
            redv[o][lane] = best; redj[o][lane] = bj;
        }
    }
    __syncthreads();
    if (tid < OPB) {
        int o = tid;
        double best = -1e300; int bj = NUM_OBJ_CLS;
        for (int g = 0; g < 31; g++) {
            double v = redv[o][g]; int j = redj[o][g];
            if (v > best || (v == best && j < bj)) { best = v; bj = j; }
        }
        preds[o0 + o] = bj;
    }
}

// ---------------- LDS-staged fp16 NT GEMM, 2-phase double-buffered (T3-minimum) ----------------
// C[n][m] = sum_k A[m][k]*B[n][k] (+bias[m] if m<biasLimit)
// 128x128 tile, BK=32, buf[2] (32 KB total LDS), 4 waves (2x2 of 64x64).
// Per iter: sync (vmcnt drain = prefetch ready) -> stage(t+1) -> ds_read+MFMA(t).
// LDS chunk c=(row,slot): holds A[row][(slot^swz(row))*8..+8), swz(r)=(r^(r>>2))&3.
template<bool SPLITM>
__global__ __launch_bounds__(256) void k_gemm(const f16* __restrict__ A, const f16* __restrict__ B,
                                              f16* __restrict__ C, const float* __restrict__ bias,
                                              int K, int lda, int ldb, int ldc,
                                              long aZ, long bZ, long cZ, int biasLimit) {
    __shared__ f16 As[2][128 * 32];
    __shared__ f16 Bs[2][128 * 32];
    long z = blockIdx.z;
    A += z * aZ; B += z * bZ; C += z * cZ;

    int tid = threadIdx.x;
    int w = tid >> 6, lane = tid & 63;
    int wm = w >> 1, wn = w & 1;
    int lr = lane & 15, lg = lane >> 4;
    int mBase = blockIdx.y * 128;
    int nBase = blockIdx.x * 128;

    // staging descriptors: tile = 512 chunks of 16B; 2 chunks/thread per operand
    const f16* aSrc[2]; const f16* bSrc[2];
    f16* aDst[2]; f16* bDst[2];
    #pragma unroll
    for (int p = 0; p < 2; p++) {
        int c = p * 256 + tid;
        int row = c >> 2, slot = c & 3;
        int g = (slot ^ ((row ^ (row >> 2)) & 3)) * 8;   // inverse-swizzled global col
        aSrc[p] = A + (size_t)(mBase + row) * lda + g;
        bSrc[p] = B + (size_t)(nBase + row) * ldb + g;
        aDst[p] = As[0] + p * 2048 + w * 512;            // wave-uniform, linear LDS dest
        bDst[p] = Bs[0] + p * 2048 + w * 512;
    }
    int swzL = ((lr & 3) ^ ((lr >> 2) & 3)) * 8;         // per-lane read swizzle (f16 units)
    f32x4 acc[4][4] = {};
    int nt = K >> 5;

    // prologue: stage tile 0 into buf 0
    #pragma unroll
    for (int p = 0; p < 2; p++) { gl_lds16(aSrc[p], aDst[p]); gl_lds16(bSrc[p], bDst[p]); }

    for (int t = 0; t < nt; t++) {
        __syncthreads();                                 // vmcnt(0) drain: buf[t&1] ready
        int cur = t & 1;
        if (t + 1 < nt) {
            int koff = (t + 1) * 32;
            int nxt = (cur ^ 1) * 4096;
            #pragma unroll
            for (int p = 0; p < 2; p++) {
                gl_lds16(aSrc[p] + koff, aDst[p] + nxt);
                gl_lds16(bSrc[p] + koff, bDst[p] + nxt);
            }
        }
        const f16* Ab = As[cur];
        const f16* Bb = Bs[cur];
        f16x8 av[4], bv[4];
        #pragma unroll
        for (int i = 0; i < 4; i++) {
            av[i] = *(const f16x8*)(Ab + (wm * 64 + i * 16 + lr) * 32 + ((lg * 8) ^ swzL));
            bv[i] = *(const f16x8*)(Bb + (wn * 64 + i * 16 + lr) * 32 + ((lg * 8) ^ swzL));
        }
        #pragma unroll
        for (int i = 0; i < 4; i++)
            #pragma unroll
            for (int jj = 0; jj < 4; jj++)
                acc[i][jj] = __builtin_amdgcn_mfma_f32_16x16x32_f16(av[i], bv[jj], acc[i][jj], 0, 0, 0);
    }

    #pragma unroll
    for (int i = 0; i < 4; i++) {
        int mb = mBase + wm * 64 + i * 16 + lg * 4;
        f32x4 bi = {};
        if (bias && mb < biasLimit) bi = *(const f32x4*)(bias + mb);
        #pragma unroll
        for (int jj = 0; jj < 4; jj++) {
            int n = nBase + wn * 64 + jj * 16 + lr;
            f16x4 hv;
            #pragma unroll
            for (int r = 0; r < 4; r++) hv[r] = (f16)(acc[i][jj][r] + bi[r]);
            if (SPLITM) {
                size_t off = ((size_t)((mb >= POOL) ? N_OBJ : 0) + n) * POOL + (mb & (POOL - 1));
                *(f16x4*)(C + off) = hv;
            } else {
                *(f16x4*)(C + (size_t)n * ldc + mb) = hv;
            }
        }
    }
}

// ---------------- final fused kernel (R2 structure: 16 rows/wave, full K) ----------------
// out[r, 0:51] = ((P_h[h[r]] + P_t[t[r]]) * U[r]) @ Wrel + b_rel + freq_bias[lbl(r)]
__global__ __launch_bounds__(256) void k_final(const f16* __restrict__ P, const float* __restrict__ U,
                                               const int* __restrict__ relp, const int* __restrict__ preds,
                                               const f16* __restrict__ wfrag, const float* __restrict__ brel,
                                               const float* __restrict__ fbias, float* __restrict__ out) {
    int w = threadIdx.x >> 6;
    int lane = threadIdx.x & 63;
    int lr = lane & 15, lg = lane >> 4;
    int r0 = blockIdx.x * 64 + w * 16;
    int arow = r0 + lr;
    int h = relp[2 * arow], t = relp[2 * arow + 1];
    const f16* ph = P + (size_t)h * POOL;
    const f16* pt = P + (size_t)(N_OBJ + t) * POOL;
    const float* u = U + (size_t)arow * POOL;
    f32x4 acc[4] = {};
    for (int ks = 0; ks < POOL / 32; ks++) {
        int ka = ks * 32 + lg * 8;
        f16x8 vh = *(const f16x8*)(ph + ka);
        f16x8 vt = *(const f16x8*)(pt + ka);
        f32x4 u0 = __builtin_nontemporal_load((const f32x4*)(u + ka));
        f32x4 u1 = __builtin_nontemporal_load((const f32x4*)(u + ka + 4));
        f16x8 a;
        #pragma unroll
        for (int jj = 0; jj < 8; jj++) {
            float uu = (jj < 4) ? u0[jj] : u1[jj - 4];
            a[jj] = (f16)(((float)vh[jj] + (float)vt[jj]) * uu);
        }
        const f16x8* bf = (const f16x8*)wfrag + (size_t)ks * 4 * 64 + lane;
        #pragma unroll
        for (int nt = 0; nt < 4; nt++)
            acc[nt] = __builtin_amdgcn_mfma_f32_16x16x32_f16(a, bf[nt * 64], acc[nt], 0, 0, 0);
    }
    #pragma unroll
    for (int r = 0; r < 4; r++) {
        int row = r0 + lg * 4 + r;
        int h2 = relp[2 * row], t2 = relp[2 * row + 1];
        int lbl = preds[h2] * NUM_OBJ_CLS + preds[t2];
        const float* fb = fbias + (size_t)lbl * N_RELCLS;
        #pragma unroll
        for (int nt = 0; nt < 4; nt++) {
            int j = nt * 16 + lr;
            if (j < N_RELCLS)
                out[(size_t)row * N_RELCLS + j] = acc[nt][r] + brel[j] + fb[j];
        }
    }
}

extern "C" void kernel_launch(void* const* d_in, const int* in_sizes, int n_in,
                              void* d_out, int out_size, void* d_ws, size_t ws_size,
                              hipStream_t stream) {
    const float* edge_ctx = (const float*)d_in[0];
    const int*   relp     = (const int*)d_in[1];
    const float* U        = (const float*)d_in[2];
    const float* Wobj     = (const float*)d_in[3];
    const float* bobj     = (const float*)d_in[4];
    const float* Wpe      = (const float*)d_in[5];
    const float* bpe      = (const float*)d_in[6];
    const float* Wcat     = (const float*)d_in[7];
    const float* bcat     = (const float*)d_in[8];
    const float* Wrel     = (const float*)d_in[9];
    const float* brel     = (const float*)d_in[10];
    const float* fbias    = (const float*)d_in[11];
    float* out = (float*)d_out;

    char* ws = (char*)d_ws;
    f16*   E16    = (f16*)(ws + WS_E16);
    f16*   Wpe16  = (f16*)(ws + WS_WPE16);
    f16*   WcatT  = (f16*)(ws + WS_WCATT);
    f16*   FT     = (f16*)(ws + WS_FT);
    f16*   P      = (f16*)(ws + WS_P);
    float* bias   = (float*)(ws + WS_BIAS);
    int*   preds  = (int*)(ws + WS_PREDS);
    f16*   wfrag  = (f16*)(ws + WS_WFRAG);

    // 1. fused prep (converts + transpose + bias + wrel_frag)
    k_prep<<<5504, 256, 0, stream>>>(edge_ctx, Wpe, Wcat, bpe, bcat, Wrel,
                                     E16, Wpe16, WcatT, bias, wfrag);
    // 2. object class argmax (f64 accum)
    k_argmax<<<N_OBJ / OPB, 256, 0, stream>>>(edge_ctx, Wobj, bobj, preds);
    // 3. fold (both parts, grid.z=2): FT[z][c][k] = sum_j Wpe16[k, z*512+j] * WcatT[c, z*512+j]
    k_gemm<false><<<dim3(POOL / 128, HIDDEN / 128, 2), 256, 0, stream>>>(
        Wpe16, WcatT, FT, nullptr, HIDDEN, 2 * HIDDEN, 2 * HIDDEN, HIDDEN,
        512L, 512L, (long)POOL * HIDDEN, 0);
    // 4. fused proj (M=8192 covers both parts): P[part][o][c] = FT[part][c] . E16[o] (+bias on part 0)
    k_gemm<true><<<dim3(N_OBJ / 128, (2 * POOL) / 128, 1), 256, 0, stream>>>(
        FT, E16, P, bias, HIDDEN, HIDDEN, HIDDEN, POOL,
        0L, 0L, 0L, POOL);
    // 5. final fused gather + union-mult + GEMM4 + freq_bias
    k_final<<<N_REL / 64, 256, 0, stream>>>(P, U, relp, preds, wfrag, brel, fbias, out);
}